// Round 1
// baseline (242.158 us; speedup 1.0000x reference)
//
#include <hip/hip_runtime.h>
#include <math.h>

#define MAXDEPTH 5
#define BSZ 512
#define DD 32000           // non-EOS tokens
#define VV (DD + 1)        // + EOS column
#define ALPHA 0.1f

// Depth-dependent KL target parameters: a = 1/denom(depth), t_ne = (1-a)/D.
// denom(depth) = sum_{i=0}^{MAXDEPTH-depth} D^i  (reference: j = MAXDEPTH..1)
__device__ __forceinline__ void depth_target(int depth, float* a_out, float* tne_out) {
    double dd = (double)DD;
    double denom = 0.0, p = 1.0;
    const int top = MAXDEPTH - depth;
    for (int i = 0; i <= top; ++i) { denom += p; p *= dd; }
    const float a = (float)(1.0 / denom);
    *a_out = a;
    *tne_out = (1.0f - a) / (float)DD;
}

// Pass 1: one block per (depth,row). Streams 3 logp rows + gumbel row,
// reduces S1, S2, T, A, B, KL-sum and the gumbel argmax; writes 6 floats.
__global__ __launch_bounds__(256) void pgr_pass1(
    const float* __restrict__ lp_all, const float* __restrict__ ln_all,
    const float* __restrict__ lq_all, const float* __restrict__ gm_all,
    const int* __restrict__ st_all, float* __restrict__ ws)
{
    const int bid = blockIdx.x;              // depth*BSZ + row
    const int tid = threadIdx.x;
    const size_t off = (size_t)bid;
    const float* __restrict__ lp  = lp_all + off * VV;
    const float* __restrict__ lnv = ln_all + off * VV;
    const float* __restrict__ lq  = lq_all + off * VV;
    const float* __restrict__ gm  = gm_all + off * (size_t)DD;
    const int st = st_all[bid];

    float S1 = 0.f, S2 = 0.f, T = 0.f, A = 0.f, B = 0.f, KL = 0.f;
    float amax = -INFINITY;
    int aidx = 0x7fffffff;

    for (int i = tid; i < DD / 4; i += 256) {
        const float4 p4 = ((const float4*)lp)[i];
        const float4 n4 = ((const float4*)lnv)[i];
        const float4 q4 = ((const float4*)lq)[i];
        const float4 g4 = ((const float4*)gm)[i];
        const float pv[4] = {p4.x, p4.y, p4.z, p4.w};
        const float nv[4] = {n4.x, n4.y, n4.z, n4.w};
        const float qv[4] = {q4.x, q4.y, q4.z, q4.w};
        const float gv[4] = {g4.x, g4.y, g4.z, g4.w};
#pragma unroll
        for (int k = 0; k < 4; ++k) {
            const float lpq = pv[k] + qv[k];
            const float e1 = __expf(lpq);      // exp(lp+lq), <= 1
            const float e2 = __expf(nv[k]);    // exp(ln),     <= 1
            const float w  = e1 * (1.f - e2);
            S1 += w;
            S2 += w * lpq;
            T  += e1;
            A  += e2 * nv[k];
            B  += e2 * e1 * nv[k];
            KL += pv[k] + nv[k] + qv[k];
            const float sel = (st == 0) ? pv[k] : ((st == 1) ? nv[k] : qv[k]);
            const float sv  = sel + gv[k];
            // strict > keeps the first occurrence within this thread's
            // increasing-index scan (matches np.argmax)
            if (sv > amax) { amax = sv; aidx = i * 4 + k; }
        }
    }

    // wave (64-lane) reduction
    const int lane = tid & 63;
    const int wv   = tid >> 6;
#pragma unroll
    for (int o = 32; o > 0; o >>= 1) {
        S1 += __shfl_down(S1, o);
        S2 += __shfl_down(S2, o);
        T  += __shfl_down(T, o);
        A  += __shfl_down(A, o);
        B  += __shfl_down(B, o);
        KL += __shfl_down(KL, o);
        const float ov = __shfl_down(amax, o);
        const int   oi = __shfl_down(aidx, o);
        if (ov > amax || (ov == amax && oi < aidx)) { amax = ov; aidx = oi; }
    }

    __shared__ float sh[4][7];
    __shared__ int   shi[4];
    if (lane == 0) {
        sh[wv][0] = S1; sh[wv][1] = S2; sh[wv][2] = T; sh[wv][3] = A;
        sh[wv][4] = B;  sh[wv][5] = KL; sh[wv][6] = amax;
        shi[wv] = aidx;
    }
    __syncthreads();

    if (tid == 0) {
        for (int w2 = 1; w2 < 4; ++w2) {
            S1 += sh[w2][0]; S2 += sh[w2][1]; T += sh[w2][2];
            A  += sh[w2][3]; B  += sh[w2][4]; KL += sh[w2][5];
            const float ov = sh[w2][6]; const int oi = shi[w2];
            if (ov > amax || (ov == amax && oi < aidx)) { amax = ov; aidx = oi; }
        }
        // EOS column (v = DD): contributes to middle/last sums + KL-eos,
        // but not to the argmax (reference argmaxes over [:, :-1]).
        const float pe = lp[DD], ne = lnv[DD], qe = lq[DD];
        {
            const float lpq = pe + qe;
            const float e1 = __expf(lpq);
            const float e2 = __expf(ne);
            const float w  = e1 * (1.f - e2);
            S1 += w; S2 += w * lpq; T += e1; A += e2 * ne; B += e2 * e1 * ne;
        }
        const float kleos = pe + ne + qe;
        const float last  = T * A - B;

        const int nxt   = aidx;
        const float lpn = lp[nxt], lnn = lnv[nxt], lqn = lq[nxt];
        const float sum3n = lpn + lnn + lqn;
        const float smlog = (st == 0) ? (lnn + lqn)
                          : (st == 1) ? (lpn + lqn)
                                      : (lpn + lnn);
        const float sm = __expf(smlog);

        const int depth = bid / BSZ;
        float a, tne;
        depth_target(depth, &a, &tne);
        const float klrow = tne * KL + a * kleos;

        float* o = ws + (size_t)bid * 6;
        o[0] = S1; o[1] = S2; o[2] = last; o[3] = klrow; o[4] = sm; o[5] = sum3n;
    }
}

// Pass 2: single block, one thread per row. kl batch-mean per depth,
// prefix logcur, backward recursion, final mean.
__global__ __launch_bounds__(BSZ) void pgr_pass2(
    const float* __restrict__ ws, float* __restrict__ out)
{
    const int r = threadIdx.x;      // row
    __shared__ float red[BSZ];
    __shared__ float klmean_sh;

    float base[MAXDEPTH], smv[MAXDEPTH];
    float logcur = 0.f;

    for (int depth = 0; depth < MAXDEPTH; ++depth) {
        const float* o = ws + ((size_t)depth * BSZ + r) * 6;
        const float S1 = o[0], S2 = o[1], last = o[2];
        const float klrow = o[3], sm = o[4], sum3n = o[5];

        red[r] = klrow;
        __syncthreads();
        for (int s = BSZ / 2; s > 0; s >>= 1) {
            if (r < s) red[r] += red[r + s];
            __syncthreads();
        }
        if (r == 0) klmean_sh = red[0] / (float)BSZ;
        __syncthreads();
        const float klmean = klmean_sh;
        __syncthreads();   // protect red[] before next depth's write

        float a, tne;
        depth_target(depth, &a, &tne);
        // C = sum_v t*log t  (D identical non-EOS entries + the EOS entry)
        const float C = (float)DD * tne * logf(tne) + a * logf(a);
        const float kl = 3.f * C - klmean;

        const float mid = S1 * logcur + S2;
        base[depth] = mid + last - ALPHA * kl;
        smv[depth]  = sm;
        logcur += sum3n;
    }

    // u_seq == 1 always: argmax is over the D non-EOS tokens, never EOS.
    float R = base[MAXDEPTH - 1];
    for (int depth = MAXDEPTH - 2; depth >= 0; --depth)
        R = R * smv[depth] + base[depth];

    red[r] = R;
    __syncthreads();
    for (int s = BSZ / 2; s > 0; s >>= 1) {
        if (r < s) red[r] += red[r + s];
        __syncthreads();
    }
    if (r == 0) out[0] = -red[0] / (float)BSZ;
}

extern "C" void kernel_launch(void* const* d_in, const int* in_sizes, int n_in,
                              void* d_out, int out_size, void* d_ws, size_t ws_size,
                              hipStream_t stream) {
    const float* lp = (const float*)d_in[0];   // logp_pos (5,512,32001)
    const float* ln = (const float*)d_in[1];   // logp_neg
    const float* lq = (const float*)d_in[2];   // logp_q
    const float* gm = (const float*)d_in[3];   // gumbel   (5,512,32000)
    const int*   st = (const int*)d_in[4];     // sampling_target (5,512)
    float* ws  = (float*)d_ws;                 // 2560 * 6 floats = 61.4 KB
    float* out = (float*)d_out;                // scalar loss

    pgr_pass1<<<MAXDEPTH * BSZ, 256, 0, stream>>>(lp, ln, lq, gm, st, ws);
    pgr_pass2<<<1, BSZ, 0, stream>>>(ws, out);
}